// Round 2
// baseline (12609.147 us; speedup 1.0000x reference)
//
#include <hip/hip_runtime.h>
#include <math.h>

// Problem constants: B=8, T=64, Cin=64, L=256, F=128, K=5 (SAME pad=2), fp32.
#define B_SZ 8
#define T_SZ 64
#define CIN 64
#define L_LEN 256
#define F_CH 128
#define K_W 5
#define LTILE 128          // l covered per block: 64 lanes x 2 l/thread
#define CH_CHUNK 64        // channels staged to LDS per chunk
#define PADL (LTILE + 4)   // +4 halo for K=5

__device__ __forceinline__ float sigmoid_f(float x) {
    return 1.0f / (1.0f + __expf(-x));
}
__device__ __forceinline__ float tanh_f(float x) {
    float a = fabsf(x);
    float e = __expf(-2.0f * a);
    float t = (1.0f - e) / (1.0f + e);
    return copysignf(t, x);
}

// One ConvLSTM timestep for one layer.
// grid = (L/128, B, F/4); block = 256 (4 waves). Each wave owns ONE f
// (wave-uniform via readfirstlane -> weights are scalar s_loads broadcast
// to all lanes). Each thread computes 2 consecutive l outputs, all 4 gates:
// per-cl ratio = 40 FMA : 20 weight dwords : 3 LDS reads. 8 independent
// acc chains for ILP; unroll-4 prefetches weights ~320 FMA-cycles ahead.
template<int C0, int CTOT>
__global__ __launch_bounds__(256)
void convlstm_step(const float* __restrict__ in0, int stride_in0_b,
                   const float* __restrict__ hprev,   // [B,F,L]
                   const float* __restrict__ W,       // [4F, CTOT, K]
                   const float* __restrict__ bias,    // [4F]
                   const float* __restrict__ c_in,    // [B,F,L]
                   float* __restrict__ c_out,         // [B,F,L]
                   float* __restrict__ h_out)         // [B,F,L] slice
{
    __shared__ float sh[CH_CHUNK * PADL];   // 64 x 132 floats = 33.8 KB

    const int tid  = threadIdx.x;
    const int lane = tid & 63;
    const int wave = tid >> 6;
    const int l0   = blockIdx.x * LTILE;
    const int b    = blockIdx.y;
    const int f    = __builtin_amdgcn_readfirstlane(blockIdx.z * 4 + wave);

    float ai0 = 0.f, ai1 = 0.f, af0 = 0.f, af1 = 0.f;
    float ao0 = 0.f, ao1 = 0.f, ag0 = 0.f, ag1 = 0.f;

    constexpr int NCHUNK = CTOT / CH_CHUNK;
    for (int ch = 0; ch < NCHUNK; ++ch) {
        const int cbase = ch * CH_CHUNK;
        // CH_CHUNK=64 divides C0 (64/128) and F, so chunks don't straddle.
        const float* src = (cbase < C0)
            ? (in0 + b * stride_in0_b + cbase * L_LEN)
            : (hprev + b * (F_CH * L_LEN) + (cbase - C0) * L_LEN);

        __syncthreads();  // protect prior chunk's LDS reads
        for (int c = wave; c < CH_CHUNK; c += 4) {
            const float* s = src + c * L_LEN;
            float* dst = sh + c * PADL;
            for (int p = lane; p < PADL; p += 64) {
                int gl = l0 + p - 2;
                dst[p] = (gl >= 0 && gl < L_LEN) ? s[gl] : 0.f;
            }
        }
        __syncthreads();

        const float* wi = W + ((0 * F_CH + f) * CTOT + cbase) * K_W;
        const float* wf = W + ((1 * F_CH + f) * CTOT + cbase) * K_W;
        const float* wo = W + ((2 * F_CH + f) * CTOT + cbase) * K_W;
        const float* wg = W + ((3 * F_CH + f) * CTOT + cbase) * K_W;
        const float* rowbase = sh + 2 * lane;

        #pragma unroll 4
        for (int cl = 0; cl < CH_CHUNK; ++cl) {
            const float* row = rowbase + cl * PADL;
            float x0 = row[0];
            float x1 = row[1];
            float x2 = row[2];
            float x3 = row[3];
            float x4 = row[4];
            float x5 = row[5];
            const float* pi = wi + cl * K_W;
            const float* pf = wf + cl * K_W;
            const float* po = wo + cl * K_W;
            const float* pg = wg + cl * K_W;

            float w;
            w = pi[0]; ai0 = fmaf(w, x0, ai0); ai1 = fmaf(w, x1, ai1);
            w = pi[1]; ai0 = fmaf(w, x1, ai0); ai1 = fmaf(w, x2, ai1);
            w = pi[2]; ai0 = fmaf(w, x2, ai0); ai1 = fmaf(w, x3, ai1);
            w = pi[3]; ai0 = fmaf(w, x3, ai0); ai1 = fmaf(w, x4, ai1);
            w = pi[4]; ai0 = fmaf(w, x4, ai0); ai1 = fmaf(w, x5, ai1);

            w = pf[0]; af0 = fmaf(w, x0, af0); af1 = fmaf(w, x1, af1);
            w = pf[1]; af0 = fmaf(w, x1, af0); af1 = fmaf(w, x2, af1);
            w = pf[2]; af0 = fmaf(w, x2, af0); af1 = fmaf(w, x3, af1);
            w = pf[3]; af0 = fmaf(w, x3, af0); af1 = fmaf(w, x4, af1);
            w = pf[4]; af0 = fmaf(w, x4, af0); af1 = fmaf(w, x5, af1);

            w = po[0]; ao0 = fmaf(w, x0, ao0); ao1 = fmaf(w, x1, ao1);
            w = po[1]; ao0 = fmaf(w, x1, ao0); ao1 = fmaf(w, x2, ao1);
            w = po[2]; ao0 = fmaf(w, x2, ao0); ao1 = fmaf(w, x3, ao1);
            w = po[3]; ao0 = fmaf(w, x3, ao0); ao1 = fmaf(w, x4, ao1);
            w = po[4]; ao0 = fmaf(w, x4, ao0); ao1 = fmaf(w, x5, ao1);

            w = pg[0]; ag0 = fmaf(w, x0, ag0); ag1 = fmaf(w, x1, ag1);
            w = pg[1]; ag0 = fmaf(w, x1, ag0); ag1 = fmaf(w, x2, ag1);
            w = pg[2]; ag0 = fmaf(w, x2, ag0); ag1 = fmaf(w, x3, ag1);
            w = pg[3]; ag0 = fmaf(w, x3, ag0); ag1 = fmaf(w, x4, ag1);
            w = pg[4]; ag0 = fmaf(w, x4, ag0); ag1 = fmaf(w, x5, ag1);
        }
    }

    // epilogue: gates + state update (2 l per thread, float2 I/O)
    const float bi = bias[0 * F_CH + f];
    const float bf = bias[1 * F_CH + f];
    const float bo = bias[2 * F_CH + f];
    const float bg = bias[3 * F_CH + f];

    float gi0 = sigmoid_f(ai0 + bi), gi1 = sigmoid_f(ai1 + bi);
    float gf0 = sigmoid_f(af0 + bf), gf1 = sigmoid_f(af1 + bf);
    float go0 = sigmoid_f(ao0 + bo), go1 = sigmoid_f(ao1 + bo);
    float gg0 = tanh_f(ag0 + bg),    gg1 = tanh_f(ag1 + bg);

    const int idx = (b * F_CH + f) * L_LEN + l0 + 2 * lane;
    float2 cprev = *(const float2*)(c_in + idx);
    float cn0 = gf0 * cprev.x + gi0 * gg0;
    float cn1 = gf1 * cprev.y + gi1 * gg1;
    float hn0 = go0 * tanh_f(cn0);
    float hn1 = go1 * tanh_f(cn1);
    *(float2*)(c_out + idx) = make_float2(cn0, cn1);
    *(float2*)(h_out + idx) = make_float2(hn0, hn1);
}

extern "C" void kernel_launch(void* const* d_in, const int* in_sizes, int n_in,
                              void* d_out, int out_size, void* d_ws, size_t ws_size,
                              hipStream_t stream)
{
    const float* x  = (const float*)d_in[0];  // [B,T,Cin,L]
    const float* W0 = (const float*)d_in[1];  // [512,192,5]
    const float* b0 = (const float*)d_in[2];  // [512]
    const float* W1 = (const float*)d_in[3];  // [512,256,5]
    const float* b1 = (const float*)d_in[4];  // [512]
    const float* h0 = (const float*)d_in[5];  // [B,F,L]
    const float* c0 = (const float*)d_in[6];
    const float* h1 = (const float*)d_in[7];
    const float* c1 = (const float*)d_in[8];
    float* out = (float*)d_out;               // [T,B,F,L]

    const int S = B_SZ * F_CH * L_LEN;        // 262144 elems per [B,F,L] slab
    float* ws    = (float*)d_ws;
    float* hs0_a = ws;                        // layer0 h ping
    float* hs0_b = ws + S;                    // layer0 h pong
    float* c0w   = ws + 2 * S;                // layer0 c state
    float* c1w   = ws + 3 * S;                // layer1 c state

    dim3 grid(L_LEN / LTILE, B_SZ, F_CH / 4); // (2, 8, 32) = 512 blocks
    dim3 block(256);

    for (int t = 0; t < T_SZ; ++t) {
        // ---- layer 0 ----
        const float* hprev0 = (t == 0) ? h0 : ((t & 1) ? hs0_a : hs0_b);
        float*       hout0  = (t & 1) ? hs0_b : hs0_a;
        const float* cin0   = (t == 0) ? c0 : c0w;
        convlstm_step<CIN, CIN + F_CH><<<grid, block, 0, stream>>>(
            x + t * CIN * L_LEN, T_SZ * CIN * L_LEN,
            hprev0, W0, b0, cin0, c0w, hout0);

        // ---- layer 1 ---- (h1 recurrent state lives in d_out[t-1])
        const float* hprev1 = (t == 0) ? h1 : (out + (size_t)(t - 1) * S);
        const float* cin1   = (t == 0) ? c1 : c1w;
        convlstm_step<F_CH, 2 * F_CH><<<grid, block, 0, stream>>>(
            hout0, F_CH * L_LEN,
            hprev1, W1, b1, cin1, c1w, out + (size_t)t * S);
    }
}

// Round 3
// 4797.683 us; speedup vs baseline: 2.6282x; 2.6282x over previous
//
#include <hip/hip_runtime.h>
#include <math.h>

// Problem: B=8, T=64, Cin=64, L=256, F=128, K=5 (SAME pad=2), fp32.
// Strategy: per (t, layer) one MFMA kernel. GEMM: M=512 (rows r=4f+g),
// N=2048 (b,l), K=5 taps x Ctot channels. fp32 emulated as bf16x2
// (AhBh + AlBh + AhBl, fp32 accumulate). LSTM epilogue fused in-lane.
#define B_SZ 8
#define T_SZ 64
#define CIN 64
#define L_LEN 256
#define F_CH 128
#define K_W 5

typedef short bf16x8 __attribute__((ext_vector_type(8)));
typedef float f32x4  __attribute__((ext_vector_type(4)));
typedef unsigned int  uint_t;
typedef unsigned short ushort_t;

__device__ __forceinline__ float sigmoid_f(float x) {
    return 1.0f / (1.0f + __expf(-x));
}
__device__ __forceinline__ float tanh_f(float x) {
    float a = fabsf(x);
    float e = __expf(-2.0f * a);
    float t = (1.0f - e) / (1.0f + e);
    return copysignf(t, x);
}
__device__ __forceinline__ ushort_t bf16rne(float f) {
    uint_t u = __float_as_uint(f);
    uint_t r = (u + 0x7FFFu + ((u >> 16) & 1u)) >> 16;
    return (ushort_t)r;
}

union FragU { uint4 q; bf16x8 v; };

// Extract hi-frag / lo-frag (8 bf16 each) from 8 packed words (hi16|lo16<<16).
__device__ __forceinline__ void split_frag(uint4 p0, uint4 p1,
                                           bf16x8& hi, bf16x8& lo) {
    uint_t a0 = p0.x, a1 = p0.y, a2 = p0.z, a3 = p0.w;
    uint_t a4 = p1.x, a5 = p1.y, a6 = p1.z, a7 = p1.w;
    FragU H, L;
    H.q.x = (a0 & 0xFFFFu) | (a1 << 16);
    H.q.y = (a2 & 0xFFFFu) | (a3 << 16);
    H.q.z = (a4 & 0xFFFFu) | (a5 << 16);
    H.q.w = (a6 & 0xFFFFu) | (a7 << 16);
    L.q.x = (a0 >> 16) | (a1 & 0xFFFF0000u);
    L.q.y = (a2 >> 16) | (a3 & 0xFFFF0000u);
    L.q.z = (a4 >> 16) | (a5 & 0xFFFF0000u);
    L.q.w = (a6 >> 16) | (a7 & 0xFFFF0000u);
    hi = H.v; lo = L.v;
}

// ---- Pre-pass: convert weights to bf16x2 in A-fragment order --------------
// A'[tap][ks][koct][r][8], r = 4f+g, ks over 32-channel chunks, koct = k/8.
// One thread per (tap,ks,koct,r) chunk -> 8 hi + 8 lo bf16.
template<int CTOT>
__global__ __launch_bounds__(256)
void convert_w(const float* __restrict__ W, ushort_t* __restrict__ Ahi,
               ushort_t* __restrict__ Alo)
{
    constexpr int KS = CTOT / 32;
    const int idx = blockIdx.x * 256 + threadIdx.x;
    if (idx >= 5 * KS * 4 * 512) return;
    const int r    = idx & 511;
    int rest       = idx >> 9;
    const int koct = rest & 3;  rest >>= 2;
    const int ks   = rest % KS;
    const int tap  = rest / KS;
    const int f = r >> 2, g = r & 3;
    const int row = g * F_CH + f;
    #pragma unroll
    for (int j = 0; j < 8; ++j) {
        int c = ks * 32 + koct * 8 + j;
        float w = W[(row * CTOT + c) * K_W + tap];
        ushort_t h = bf16rne(w);
        ushort_t l = bf16rne(w - __uint_as_float(((uint_t)h) << 16));
        Ahi[idx * 8 + j] = h;
        Alo[idx * 8 + j] = l;
    }
}

__global__ __launch_bounds__(256)
void remap_bias(const float* __restrict__ b0, const float* __restrict__ b1,
                float* __restrict__ br0, float* __restrict__ br1)
{
    int r = blockIdx.x * 256 + threadIdx.x;
    if (r < 512)       br0[r] = b0[(r & 3) * F_CH + (r >> 2)];
    else { r -= 512;   br1[r] = b1[(r & 3) * F_CH + (r >> 2)]; }
}

// ---- Main: one ConvLSTM step for one layer (MFMA) -------------------------
// grid = 128 blocks: bit6 = m-block (256 rows), low6 = n-group (b, 32 l).
// Block = 4 waves, wave m=64 (4 mtiles of 16) x n=32 (2 nfrags of 16).
template<int C0, int CTOT>
__global__ __launch_bounds__(256)
void step_mfma(const float* __restrict__ in0, int in0_b_stride,
               const float* __restrict__ hprev,
               const ushort_t* __restrict__ Ahi, const ushort_t* __restrict__ Alo,
               const float* __restrict__ biasr,
               const float* __restrict__ c_in,
               float* __restrict__ c_out, float* __restrict__ h_out)
{
    constexpr int KS = CTOT / 32;
    constexpr int STRIDE = CTOT + 4;          // b32 units, %4==0 for b128 align
    __shared__ __align__(16) uint_t sh[36 * STRIDE];

    const int tid  = threadIdx.x;
    const int nblk = blockIdx.x & 63;
    const int mblk = blockIdx.x >> 6;
    const int b    = nblk >> 3;
    const int l0   = (nblk & 7) << 5;

    // Stage activation tile: rows lp=0..35 (global l = l0+lp-2), cols c,
    // packed (hi | lo<<16). Halo rows zero -> no bounds checks in K-loop.
    for (int i = tid; i < CTOT * 36; i += 256) {
        int c = i / 36, lp = i - c * 36;
        int gl = l0 + lp - 2;
        float v = 0.f;
        if (gl >= 0 && gl < L_LEN)
            v = (c < C0) ? in0[b * in0_b_stride + c * L_LEN + gl]
                         : hprev[(b * F_CH + (c - C0)) * L_LEN + gl];
        ushort_t h = bf16rne(v);
        ushort_t l = bf16rne(v - __uint_as_float(((uint_t)h) << 16));
        sh[lp * STRIDE + c] = (uint_t)h | (((uint_t)l) << 16);
    }
    __syncthreads();

    const int wave = tid >> 6, lane = tid & 63;
    const int l16 = lane & 15, oct = lane >> 4;
    const int mbase = mblk * 256 + wave * 64;

    f32x4 accA[4][2];   // AhBh
    f32x4 accB[4][2];   // AlBh + AhBl
    #pragma unroll
    for (int mt = 0; mt < 4; ++mt)
        for (int nf = 0; nf < 2; ++nf) {
            accA[mt][nf] = (f32x4)0.0f;
            accB[mt][nf] = (f32x4)0.0f;
        }

    const uint4* AH4 = (const uint4*)Ahi;
    const uint4* AL4 = (const uint4*)Alo;
    const uint4* shq = (const uint4*)sh;

    #pragma unroll 2
    for (int kk = 0; kk < 5 * KS; ++kk) {
        const int tap = kk / KS;
        const int ks  = kk - tap * KS;
        // B fragments from LDS (rows shifted by tap; 8 channels per lane)
        const int c4 = ks * 8 + oct * 2;
        const int r0 = (l16 + tap)      * (STRIDE / 4) + c4;
        const int r1 = (l16 + 16 + tap) * (STRIDE / 4) + c4;
        bf16x8 bh0, bl0, bh1, bl1;
        split_frag(shq[r0], shq[r0 + 1], bh0, bl0);
        split_frag(shq[r1], shq[r1 + 1], bh1, bl1);
        // A fragments from global (L2-hot, coalesced 16B/lane)
        const int abase = ((tap * KS + ks) * 4 + oct) * 512 + mbase + l16;
        bf16x8 ah[4], al[4];
        #pragma unroll
        for (int mt = 0; mt < 4; ++mt) {
            FragU th, tl;
            th.q = AH4[abase + 16 * mt]; ah[mt] = th.v;
            tl.q = AL4[abase + 16 * mt]; al[mt] = tl.v;
        }
        #pragma unroll
        for (int mt = 0; mt < 4; ++mt) {
            accA[mt][0] = __builtin_amdgcn_mfma_f32_16x16x32_bf16(ah[mt], bh0, accA[mt][0], 0, 0, 0);
            accA[mt][1] = __builtin_amdgcn_mfma_f32_16x16x32_bf16(ah[mt], bh1, accA[mt][1], 0, 0, 0);
        }
        #pragma unroll
        for (int mt = 0; mt < 4; ++mt) {
            accB[mt][0] = __builtin_amdgcn_mfma_f32_16x16x32_bf16(al[mt], bh0, accB[mt][0], 0, 0, 0);
            accB[mt][1] = __builtin_amdgcn_mfma_f32_16x16x32_bf16(al[mt], bh1, accB[mt][1], 0, 0, 0);
        }
        #pragma unroll
        for (int mt = 0; mt < 4; ++mt) {
            accB[mt][0] = __builtin_amdgcn_mfma_f32_16x16x32_bf16(ah[mt], bl0, accB[mt][0], 0, 0, 0);
            accB[mt][1] = __builtin_amdgcn_mfma_f32_16x16x32_bf16(ah[mt], bl1, accB[mt][1], 0, 0, 0);
        }
    }

    // Epilogue: C/D row = 4*oct + reg within mtile; reg = gate (r = 4f+g).
    #pragma unroll
    for (int mt = 0; mt < 4; ++mt) {
        const int rbase = mbase + 16 * mt + 4 * oct;   // rows rbase..rbase+3
        const float4 b4 = *(const float4*)(biasr + rbase);
        const int f = rbase >> 2;
        #pragma unroll
        for (int nf = 0; nf < 2; ++nf) {
            float pi = accA[mt][nf][0] + accB[mt][nf][0] + b4.x;
            float pf = accA[mt][nf][1] + accB[mt][nf][1] + b4.y;
            float po = accA[mt][nf][2] + accB[mt][nf][2] + b4.z;
            float pg = accA[mt][nf][3] + accB[mt][nf][3] + b4.w;
            float gi = sigmoid_f(pi);
            float gf = sigmoid_f(pf);
            float go = sigmoid_f(po);
            float gg = tanh_f(pg);
            const int idx = (b * F_CH + f) * L_LEN + l0 + nf * 16 + l16;
            float cp = c_in[idx];
            float cn = gf * cp + gi * gg;
            float hn = go * tanh_f(cn);
            c_out[idx] = cn;
            h_out[idx] = hn;
        }
    }
}

extern "C" void kernel_launch(void* const* d_in, const int* in_sizes, int n_in,
                              void* d_out, int out_size, void* d_ws, size_t ws_size,
                              hipStream_t stream)
{
    const float* x  = (const float*)d_in[0];  // [B,T,Cin,L]
    const float* W0 = (const float*)d_in[1];  // [512,192,5]
    const float* b0 = (const float*)d_in[2];  // [512]
    const float* W1 = (const float*)d_in[3];  // [512,256,5]
    const float* b1 = (const float*)d_in[4];  // [512]
    const float* h0 = (const float*)d_in[5];  // [B,F,L]
    const float* c0 = (const float*)d_in[6];
    const float* h1 = (const float*)d_in[7];
    const float* c1 = (const float*)d_in[8];
    float* out = (float*)d_out;               // [T,B,F,L]

    const int S = B_SZ * F_CH * L_LEN;        // 262144
    float* ws    = (float*)d_ws;
    float* hs0_a = ws;
    float* hs0_b = ws + S;
    float* c0w   = ws + 2 * S;
    float* c1w   = ws + 3 * S;
    float* br0   = ws + 4 * S;
    float* br1   = br0 + 512;
    ushort_t* Ahi0 = (ushort_t*)(ws + 4 * S + 1024);
    const int N0 = 512 * 192 * 5;             // 491520
    const int N1 = 512 * 256 * 5;             // 655360
    ushort_t* Alo0 = Ahi0 + N0;
    ushort_t* Ahi1 = Alo0 + N0;
    ushort_t* Alo1 = Ahi1 + N1;

    // Pre-pass: weight conversion + bias remap (every launch; graph-safe).
    convert_w<192><<<dim3((5*6*4*512 + 255)/256), dim3(256), 0, stream>>>(W0, Ahi0, Alo0);
    convert_w<256><<<dim3((5*8*4*512 + 255)/256), dim3(256), 0, stream>>>(W1, Ahi1, Alo1);
    remap_bias<<<dim3(4), dim3(256), 0, stream>>>(b0, b1, br0, br1);

    dim3 grid(128), block(256);
    for (int t = 0; t < T_SZ; ++t) {
        const float* hprev0 = (t == 0) ? h0 : ((t & 1) ? hs0_a : hs0_b);
        float*       hout0  = (t & 1) ? hs0_b : hs0_a;
        const float* cin0   = (t == 0) ? c0 : c0w;
        step_mfma<CIN, CIN + F_CH><<<grid, block, 0, stream>>>(
            x + t * CIN * L_LEN, T_SZ * CIN * L_LEN,
            hprev0, Ahi0, Alo0, br0, cin0, c0w, hout0);

        const float* hprev1 = (t == 0) ? h1 : (out + (size_t)(t - 1) * S);
        const float* cin1   = (t == 0) ? c1 : c1w;
        step_mfma<F_CH, 2 * F_CH><<<grid, block, 0, stream>>>(
            hout0, F_CH * L_LEN,
            hprev1, Ahi1, Alo1, br1, cin1, c1w, out + (size_t)t * S);
    }
}

// Round 4
// 3978.232 us; speedup vs baseline: 3.1695x; 1.2060x over previous
//
#include <hip/hip_runtime.h>
#include <math.h>

// Problem: B=8, T=64, Cin=64, L=256, F=128, K=5 (SAME pad=2), fp32.
// MFMA per (t,layer): GEMM M=512 (rows r=4f+g), N=2048 (b,l), K=5*Ctot.
// fp32 as bf16x2 (AhBh+AlBh+AhBl, fp32 acc). Wave tile m64 x n64, 4 waves
// per block = 4 K-quarters, LDS reduction, fused LSTM epilogue.
#define B_SZ 8
#define T_SZ 64
#define CIN 64
#define L_LEN 256
#define F_CH 128
#define K_W 5
#define S_BFL (B_SZ * F_CH * L_LEN)   // 262144

typedef short bf16x8 __attribute__((ext_vector_type(8)));
typedef float f32x4  __attribute__((ext_vector_type(4)));
typedef unsigned int  uint_t;
typedef unsigned short ushort_t;

__device__ __forceinline__ float sigmoid_f(float x) {
    return 1.0f / (1.0f + __expf(-x));
}
__device__ __forceinline__ float tanh_f(float x) {
    float a = fabsf(x);
    float e = __expf(-2.0f * a);
    float t = (1.0f - e) / (1.0f + e);
    return copysignf(t, x);
}
__device__ __forceinline__ ushort_t bf16rne(float f) {
    uint_t u = __float_as_uint(f);
    uint_t r = (u + 0x7FFFu + ((u >> 16) & 1u)) >> 16;
    return (ushort_t)r;
}
// packed word = hi_bf16 | lo_bf16 << 16
__device__ __forceinline__ uint_t pack_f32(float v) {
    ushort_t h = bf16rne(v);
    float hf = __uint_as_float(((uint_t)h) << 16);
    ushort_t l = bf16rne(v - hf);
    return (uint_t)h | (((uint_t)l) << 16);
}

union FragU { uint4 q; bf16x8 v; f32x4 f; float4 f4; };

// ---- Pre-pass: weights -> bf16x2 in A-fragment order ----------------------
// A'[kk=tap*KS+ks][koct][512 rows r=4f+g][8 bf16], hi and lo arrays.
template<int CTOT>
__global__ __launch_bounds__(256)
void convert_w(const float* __restrict__ W, ushort_t* __restrict__ Ahi,
               ushort_t* __restrict__ Alo)
{
    constexpr int KS = CTOT / 32;
    const int idx = blockIdx.x * 256 + threadIdx.x;
    if (idx >= 5 * KS * 4 * 512) return;
    const int r    = idx & 511;
    int rest       = idx >> 9;
    const int koct = rest & 3;  rest >>= 2;
    const int ks   = rest % KS;
    const int tap  = rest / KS;
    const int f = r >> 2, g = r & 3;
    const int row = g * F_CH + f;
    #pragma unroll
    for (int j = 0; j < 8; ++j) {
        int c = ks * 32 + koct * 8 + j;
        float w = W[(row * CTOT + c) * K_W + tap];
        ushort_t h = bf16rne(w);
        ushort_t l = bf16rne(w - __uint_as_float(((uint_t)h) << 16));
        Ahi[idx * 8 + j] = h;
        Alo[idx * 8 + j] = l;
    }
}

__global__ __launch_bounds__(256)
void remap_bias(const float* __restrict__ b0, const float* __restrict__ b1,
                float* __restrict__ br0, float* __restrict__ br1)
{
    int r = blockIdx.x * 256 + threadIdx.x;
    if (r < 512)       br0[r] = b0[(r & 3) * F_CH + (r >> 2)];
    else { r -= 512;   br1[r] = b1[(r & 3) * F_CH + (r >> 2)]; }
}

__global__ __launch_bounds__(256)
void pack_init(const float* __restrict__ h0, const float* __restrict__ h1,
               uint_t* __restrict__ hp0, uint_t* __restrict__ hp1)
{
    int i = blockIdx.x * 256 + threadIdx.x;
    if (i < S_BFL) { hp0[i] = pack_f32(h0[i]); hp1[i] = pack_f32(h1[i]); }
}

// ---- Main step kernel -----------------------------------------------------
// grid = 256: mblk = bx>>5 (8 x 64 rows), nblk = bx&31 (b = nblk>>2,
// l0 = (nblk&3)*64). Block = 4 waves = 4 K-quarters of the same m64n64 tile.
template<int C0, int CTOT, bool IN0_F32>
__global__ __launch_bounds__(256, 1)
void step_mfma(const float* __restrict__ in0f, int in0_b_stride,
               const uint_t* __restrict__ in0p,
               const uint_t* __restrict__ hprevp,
               const ushort_t* __restrict__ Ahi, const ushort_t* __restrict__ Alo,
               const float* __restrict__ biasr,
               const float* __restrict__ c_in, float* __restrict__ c_out,
               float* __restrict__ h_out_f32,   // null for layer 0
               uint_t* __restrict__ hp_out)
{
    constexpr int KS = CTOT / 32;
    constexpr int KK = 5 * KS;
    constexpr int STRIDE = CTOT + 4;             // words; %4==0 (b128 align)
    constexpr int TILE_W = 68 * STRIDE;
    constexpr int SH_WORDS = (TILE_W > 16384) ? TILE_W : 16384;
    __shared__ __align__(16) uint_t sh[SH_WORDS];

    const int tid  = threadIdx.x;
    const int nblk = blockIdx.x & 31;
    const int mblk = blockIdx.x >> 5;
    const int b    = nblk >> 2;
    const int l0   = (nblk & 3) << 6;

    // Stage activation tile: rows lp=0..67 (l = l0+lp-2), cols = channels,
    // packed bf16x2 words. Halo zero-filled.
    for (int i = tid; i < 68 * CTOT; i += 256) {
        const int c = i / 68, lp = i - c * 68;
        const int gl = l0 + lp - 2;
        uint_t w = 0;
        if (gl >= 0 && gl < L_LEN) {
            if (c < C0) {
                if (IN0_F32) w = pack_f32(in0f[b * in0_b_stride + c * L_LEN + gl]);
                else         w = in0p[(b * C0 + c) * L_LEN + gl];
            } else {
                w = hprevp[(b * F_CH + (c - C0)) * L_LEN + gl];
            }
        }
        sh[lp * STRIDE + c] = w;
    }
    __syncthreads();

    const int q    = tid >> 6;      // wave = K-quarter
    const int lane = tid & 63;
    const int l16  = lane & 15, oct = lane >> 4;
    const int mrow = mblk * 64 + l16;
    const int k_lo = (q * KK) / 4, k_hi = ((q + 1) * KK) / 4;

    f32x4 acc[4][4];
    #pragma unroll
    for (int mt = 0; mt < 4; ++mt)
        #pragma unroll
        for (int nf = 0; nf < 4; ++nf) acc[mt][nf] = (f32x4)0.0f;

    const uint4* AH4 = (const uint4*)Ahi;
    const uint4* AL4 = (const uint4*)Alo;
    const uint4* shq = (const uint4*)sh;

    uint4 A0[8], A1[8];
    auto loadA = [&](int kk, uint4* dst) {
        const int base = (kk * 4 + oct) * 512 + mrow;
        #pragma unroll
        for (int mt = 0; mt < 4; ++mt) {
            dst[2 * mt]     = AH4[base + 16 * mt];
            dst[2 * mt + 1] = AL4[base + 16 * mt];
        }
    };
    auto body = [&](int kk, uint4* A) {
        const int tap = kk / KS, ks = kk - tap * KS;
        const int cb  = ks * 8 + oct * 2;
        bf16x8 bh[4], bl[4];
        #pragma unroll
        for (int nf = 0; nf < 4; ++nf) {
            const int r = (l16 + 16 * nf + tap) * (STRIDE / 4) + cb;
            uint4 p0 = shq[r], p1 = shq[r + 1];
            FragU H, L;
            H.q.x = __builtin_amdgcn_perm(p0.y, p0.x, 0x05040100u);
            H.q.y = __builtin_amdgcn_perm(p0.w, p0.z, 0x05040100u);
            H.q.z = __builtin_amdgcn_perm(p1.y, p1.x, 0x05040100u);
            H.q.w = __builtin_amdgcn_perm(p1.w, p1.z, 0x05040100u);
            L.q.x = __builtin_amdgcn_perm(p0.y, p0.x, 0x07060302u);
            L.q.y = __builtin_amdgcn_perm(p0.w, p0.z, 0x07060302u);
            L.q.z = __builtin_amdgcn_perm(p1.y, p1.x, 0x07060302u);
            L.q.w = __builtin_amdgcn_perm(p1.w, p1.z, 0x07060302u);
            bh[nf] = H.v; bl[nf] = L.v;
        }
        #pragma unroll
        for (int mt = 0; mt < 4; ++mt) {
            FragU TH, TL; TH.q = A[2 * mt]; TL.q = A[2 * mt + 1];
            bf16x8 ah = TH.v, al = TL.v;
            #pragma unroll
            for (int nf = 0; nf < 4; ++nf) {
                acc[mt][nf] = __builtin_amdgcn_mfma_f32_16x16x32_bf16(ah, bh[nf], acc[mt][nf], 0, 0, 0);
                acc[mt][nf] = __builtin_amdgcn_mfma_f32_16x16x32_bf16(al, bh[nf], acc[mt][nf], 0, 0, 0);
                acc[mt][nf] = __builtin_amdgcn_mfma_f32_16x16x32_bf16(ah, bl[nf], acc[mt][nf], 0, 0, 0);
            }
        }
    };

    // Software pipeline: A for kk+1 in flight while MFMAing kk.
    loadA(k_lo, A0);
    for (int kk = k_lo; kk < k_hi; kk += 2) {
        loadA(kk + 1 < k_hi ? kk + 1 : kk, A1);
        body(kk, A0);
        loadA(kk + 2 < k_hi ? kk + 2 : kk, A0);
        if (kk + 1 < k_hi) body(kk + 1, A1);
    }

    // Cross-wave K-reduction through LDS (aliases staging tile).
    __syncthreads();
    float4* scratch = (float4*)sh;
    #pragma unroll
    for (int mt = 0; mt < 4; ++mt)
        #pragma unroll
        for (int nf = 0; nf < 4; ++nf) {
            FragU u; u.f = acc[mt][nf];
            scratch[(q * 16 + mt * 4 + nf) * 64 + lane] = u.f4;
        }
    __syncthreads();

    // Wave q finalizes n-columns [l0+16q, l0+16q+15] for all 4 mtiles.
    #pragma unroll
    for (int mt = 0; mt < 4; ++mt) {
        float4 s = scratch[(mt * 4 + q) * 64 + lane];
        #pragma unroll
        for (int w = 1; w < 4; ++w) {
            float4 p = scratch[(w * 16 + mt * 4 + q) * 64 + lane];
            s.x += p.x; s.y += p.y; s.z += p.z; s.w += p.w;
        }
        const int rbase = mblk * 64 + mt * 16 + 4 * oct;    // rows rbase..+3
        const float4 b4 = *(const float4*)(biasr + rbase);
        const int f = rbase >> 2;
        float gi = sigmoid_f(s.x + b4.x);
        float gf = sigmoid_f(s.y + b4.y);
        float go = sigmoid_f(s.z + b4.z);
        float gg = tanh_f(s.w + b4.w);
        const int l   = l0 + q * 16 + l16;
        const int idx = (b * F_CH + f) * L_LEN + l;
        float cp = c_in[idx];
        float cn = gf * cp + gi * gg;
        float hn = go * tanh_f(cn);
        c_out[idx] = cn;
        if (h_out_f32) h_out_f32[idx] = hn;
        hp_out[idx] = pack_f32(hn);
    }
}

extern "C" void kernel_launch(void* const* d_in, const int* in_sizes, int n_in,
                              void* d_out, int out_size, void* d_ws, size_t ws_size,
                              hipStream_t stream)
{
    const float* x  = (const float*)d_in[0];  // [B,T,Cin,L]
    const float* W0 = (const float*)d_in[1];  // [512,192,5]
    const float* b0 = (const float*)d_in[2];  // [512]
    const float* W1 = (const float*)d_in[3];  // [512,256,5]
    const float* b1 = (const float*)d_in[4];  // [512]
    const float* h0 = (const float*)d_in[5];  // [B,F,L]
    const float* c0 = (const float*)d_in[6];
    const float* h1 = (const float*)d_in[7];
    const float* c1 = (const float*)d_in[8];
    float* out = (float*)d_out;               // [T,B,F,L]

    const int S = S_BFL;
    float* ws  = (float*)d_ws;
    float* c0w = ws;                          // S floats
    float* c1w = ws + S;                      // S floats
    float* br0 = ws + 2 * S;                  // 512
    float* br1 = br0 + 512;
    uint_t* hp0a = (uint_t*)(ws + 2 * S + 1024);
    uint_t* hp0b = hp0a + S;
    uint_t* hp1a = hp0b + S;
    uint_t* hp1b = hp1a + S;
    ushort_t* Ahi0 = (ushort_t*)(hp1b + S);
    const int N0 = 512 * 192 * 5;             // 491520
    const int N1 = 512 * 256 * 5;             // 655360
    ushort_t* Alo0 = Ahi0 + N0;
    ushort_t* Ahi1 = Alo0 + N0;
    ushort_t* Alo1 = Ahi1 + N1;

    // Pre-pass (graph-safe, every call).
    convert_w<192><<<dim3(240), dim3(256), 0, stream>>>(W0, Ahi0, Alo0);
    convert_w<256><<<dim3(320), dim3(256), 0, stream>>>(W1, Ahi1, Alo1);
    remap_bias<<<dim3(4), dim3(256), 0, stream>>>(b0, b1, br0, br1);
    pack_init<<<dim3((S + 255) / 256), dim3(256), 0, stream>>>(h0, h1, hp0b, hp1b);

    dim3 grid(256), block(256);
    for (int t = 0; t < T_SZ; ++t) {
        uint_t* hp0r = (t & 1) ? hp0a : hp0b;
        uint_t* hp0w = (t & 1) ? hp0b : hp0a;
        uint_t* hp1r = (t & 1) ? hp1a : hp1b;
        uint_t* hp1w = (t & 1) ? hp1b : hp1a;

        step_mfma<CIN, 192, true><<<grid, block, 0, stream>>>(
            x + t * CIN * L_LEN, T_SZ * CIN * L_LEN, (const uint_t*)nullptr,
            hp0r, Ahi0, Alo0, br0,
            t ? (const float*)c0w : c0, c0w,
            (float*)nullptr, hp0w);

        step_mfma<F_CH, 256, false><<<grid, block, 0, stream>>>(
            (const float*)nullptr, 0, hp0w,
            hp1r, Ahi1, Alo1, br1,
            t ? (const float*)c1w : c1, c1w,
            out + (size_t)t * S, hp1w);
    }
}

// Round 5
// 1844.540 us; speedup vs baseline: 6.8359x; 2.1568x over previous
//
#include <hip/hip_runtime.h>
#include <math.h>

// Problem: B=8, T=64, Cin=64, L=256, F=128, K=5 (SAME pad=2), fp32.
// MFMA per (t,layer): GEMM M=512 (rows r=4f+g), N=2048 (b,l), K=5*Ctot.
// fp32 as bf16x2 (AhBh+AlBh+AhBl, fp32 acc). Block = m64 x n32 tile,
// 4 waves = 4 K-quarters, LDS reduction, fused LSTM epilogue.
// Grid 512 = 2 blocks/CU (8 waves/CU). mblk = bx&7 pins weight slices
// per-XCD (round-robin dispatch) for L2 residency.
#define B_SZ 8
#define T_SZ 64
#define CIN 64
#define L_LEN 256
#define F_CH 128
#define K_W 5
#define S_BFL (B_SZ * F_CH * L_LEN)   // 262144

typedef short bf16x8 __attribute__((ext_vector_type(8)));
typedef float f32x4  __attribute__((ext_vector_type(4)));
typedef unsigned int  uint_t;
typedef unsigned short ushort_t;

__device__ __forceinline__ float sigmoid_f(float x) {
    return 1.0f / (1.0f + __expf(-x));
}
__device__ __forceinline__ float tanh_f(float x) {
    float a = fabsf(x);
    float e = __expf(-2.0f * a);
    float t = (1.0f - e) / (1.0f + e);
    return copysignf(t, x);
}
__device__ __forceinline__ ushort_t bf16rne(float f) {
    uint_t u = __float_as_uint(f);
    uint_t r = (u + 0x7FFFu + ((u >> 16) & 1u)) >> 16;
    return (ushort_t)r;
}
// packed word = hi_bf16 | lo_bf16 << 16
__device__ __forceinline__ uint_t pack_f32(float v) {
    ushort_t h = bf16rne(v);
    float hf = __uint_as_float(((uint_t)h) << 16);
    ushort_t l = bf16rne(v - hf);
    return (uint_t)h | (((uint_t)l) << 16);
}

union FragU { uint4 q; bf16x8 v; f32x4 f; float4 f4; };

// ---- Pre-pass: weights -> bf16x2 in A-fragment order ----------------------
// A'[kk=tap*KS+ks][koct][512 rows r=4f+g][8 bf16], hi and lo arrays.
template<int CTOT>
__global__ __launch_bounds__(256)
void convert_w(const float* __restrict__ W, ushort_t* __restrict__ Ahi,
               ushort_t* __restrict__ Alo)
{
    constexpr int KS = CTOT / 32;
    const int idx = blockIdx.x * 256 + threadIdx.x;
    if (idx >= 5 * KS * 4 * 512) return;
    const int r    = idx & 511;
    int rest       = idx >> 9;
    const int koct = rest & 3;  rest >>= 2;
    const int ks   = rest % KS;
    const int tap  = rest / KS;
    const int f = r >> 2, g = r & 3;
    const int row = g * F_CH + f;
    #pragma unroll
    for (int j = 0; j < 8; ++j) {
        int c = ks * 32 + koct * 8 + j;
        float w = W[(row * CTOT + c) * K_W + tap];
        ushort_t h = bf16rne(w);
        ushort_t l = bf16rne(w - __uint_as_float(((uint_t)h) << 16));
        Ahi[idx * 8 + j] = h;
        Alo[idx * 8 + j] = l;
    }
}

__global__ __launch_bounds__(256)
void remap_bias(const float* __restrict__ b0, const float* __restrict__ b1,
                float* __restrict__ br0, float* __restrict__ br1)
{
    int r = blockIdx.x * 256 + threadIdx.x;
    if (r < 512)       br0[r] = b0[(r & 3) * F_CH + (r >> 2)];
    else { r -= 512;   br1[r] = b1[(r & 3) * F_CH + (r >> 2)]; }
}

__global__ __launch_bounds__(256)
void pack_init(const float* __restrict__ h0, const float* __restrict__ h1,
               uint_t* __restrict__ hp0, uint_t* __restrict__ hp1)
{
    int i = blockIdx.x * 256 + threadIdx.x;
    if (i < S_BFL) { hp0[i] = pack_f32(h0[i]); hp1[i] = pack_f32(h1[i]); }
}

// ---- Main step kernel -----------------------------------------------------
// grid = 512: mblk = bx&7 (64 rows, XCD-pinned), nblk = bx>>3:
// b = nblk>>3, l0 = (nblk&7)*32. 4 waves = 4 K-quarters of one m64n32 tile.
template<int C0, int CTOT, bool IN0_F32>
__global__ __launch_bounds__(256, 2)
void step_mfma(const float* __restrict__ in0f, int in0_b_stride,
               const uint_t* __restrict__ in0p,
               const uint_t* __restrict__ hprevp,
               const ushort_t* __restrict__ Ahi, const ushort_t* __restrict__ Alo,
               const float* __restrict__ biasr,
               const float* __restrict__ c_in, float* __restrict__ c_out,
               float* __restrict__ h_out_f32,   // null for layer 0
               uint_t* __restrict__ hp_out)
{
    constexpr int KS = CTOT / 32;
    constexpr int KK = 5 * KS;
    constexpr int STRIDE = CTOT + 4;             // words; %4==0 (b128 align)
    constexpr int TILE_W = 36 * STRIDE;          // layer1: 9360 w = 37.4 KB
    constexpr int RED_W  = 4 * 8 * 64 * 4;       // reduce scratch: 8192 words
    constexpr int SH_WORDS = (TILE_W > RED_W) ? TILE_W : RED_W;
    __shared__ __align__(16) uint_t sh[SH_WORDS];

    const int tid  = threadIdx.x;
    const int mblk = blockIdx.x & 7;             // XCD-pinned weight slice
    const int nblk = blockIdx.x >> 3;
    const int b    = nblk >> 3;
    const int l0   = (nblk & 7) << 5;

    // ---- Batched staging: rows lp=0..35 (l = l0+lp-2), cols = channels ----
    // Load phase issues U independent loads (clamped addresses), then one
    // wait covers the whole batch of LDS writes (select-zero for halo).
    constexpr int TOT = 36 * CTOT;               // 2304*U-divisible: 9216/6912
    constexpr int U = 9;
    for (int i0 = tid; i0 < TOT; i0 += 256 * U) {
        uint_t v[U];
        #pragma unroll
        for (int u = 0; u < U; ++u) {
            const int i  = i0 + u * 256;
            const int c  = i / 36, lp = i - c * 36;
            const int gl = l0 + lp - 2;
            const int glc = min(max(gl, 0), L_LEN - 1);
            if (IN0_F32) {
                const float* s = (c < C0) ? (in0f + b * in0_b_stride + c * L_LEN)
                                          : nullptr;
                v[u] = (c < C0) ? __float_as_uint(s[glc])
                                : hprevp[(b * F_CH + (c - C0)) * L_LEN + glc];
            } else {
                v[u] = (c < C0) ? in0p[(b * C0 + c) * L_LEN + glc]
                                : hprevp[(b * F_CH + (c - C0)) * L_LEN + glc];
            }
        }
        #pragma unroll
        for (int u = 0; u < U; ++u) {
            const int i  = i0 + u * 256;
            const int c  = i / 36, lp = i - c * 36;
            const int gl = l0 + lp - 2;
            uint_t w = v[u];
            if (IN0_F32 && c < C0) w = pack_f32(__uint_as_float(w));
            if (gl < 0 || gl >= L_LEN) w = 0u;
            sh[lp * STRIDE + c] = w;
        }
    }
    __syncthreads();

    const int q    = tid >> 6;      // wave = K-quarter
    const int lane = tid & 63;
    const int l16  = lane & 15, oct = lane >> 4;
    const int mrow = mblk * 64 + l16;
    const int k_lo = (q * KK) / 4, k_hi = ((q + 1) * KK) / 4;

    f32x4 acc[4][2];
    #pragma unroll
    for (int mt = 0; mt < 4; ++mt)
        #pragma unroll
        for (int nf = 0; nf < 2; ++nf) acc[mt][nf] = (f32x4)0.0f;

    const uint4* AH4 = (const uint4*)Ahi;
    const uint4* AL4 = (const uint4*)Alo;
    const uint4* shq = (const uint4*)sh;

    uint4 A0[8], A1[8];
    auto loadA = [&](int kk, uint4* dst) {
        const int base = (kk * 4 + oct) * 512 + mrow;
        #pragma unroll
        for (int mt = 0; mt < 4; ++mt) {
            dst[2 * mt]     = AH4[base + 16 * mt];
            dst[2 * mt + 1] = AL4[base + 16 * mt];
        }
    };
    auto body = [&](int kk, uint4* A) {
        const int tap = kk / KS, ks = kk - tap * KS;
        const int cb  = ks * 8 + oct * 2;
        bf16x8 bh[2], bl[2];
        #pragma unroll
        for (int nf = 0; nf < 2; ++nf) {
            const int r = (l16 + 16 * nf + tap) * (STRIDE / 4) + cb;
            uint4 p0 = shq[r], p1 = shq[r + 1];
            FragU H, L;
            H.q.x = __builtin_amdgcn_perm(p0.y, p0.x, 0x05040100u);
            H.q.y = __builtin_amdgcn_perm(p0.w, p0.z, 0x05040100u);
            H.q.z = __builtin_amdgcn_perm(p1.y, p1.x, 0x05040100u);
            H.q.w = __builtin_amdgcn_perm(p1.w, p1.z, 0x05040100u);
            L.q.x = __builtin_amdgcn_perm(p0.y, p0.x, 0x07060302u);
            L.q.y = __builtin_amdgcn_perm(p0.w, p0.z, 0x07060302u);
            L.q.z = __builtin_amdgcn_perm(p1.y, p1.x, 0x07060302u);
            L.q.w = __builtin_amdgcn_perm(p1.w, p1.z, 0x07060302u);
            bh[nf] = H.v; bl[nf] = L.v;
        }
        #pragma unroll
        for (int mt = 0; mt < 4; ++mt) {
            FragU TH, TL; TH.q = A[2 * mt]; TL.q = A[2 * mt + 1];
            bf16x8 ah = TH.v, al = TL.v;
            #pragma unroll
            for (int nf = 0; nf < 2; ++nf) {
                acc[mt][nf] = __builtin_amdgcn_mfma_f32_16x16x32_bf16(ah, bh[nf], acc[mt][nf], 0, 0, 0);
                acc[mt][nf] = __builtin_amdgcn_mfma_f32_16x16x32_bf16(al, bh[nf], acc[mt][nf], 0, 0, 0);
                acc[mt][nf] = __builtin_amdgcn_mfma_f32_16x16x32_bf16(ah, bl[nf], acc[mt][nf], 0, 0, 0);
            }
        }
    };

    // Software pipeline: A for kk+1 in flight while MFMAing kk.
    loadA(k_lo, A0);
    for (int kk = k_lo; kk < k_hi; kk += 2) {
        loadA(kk + 1 < k_hi ? kk + 1 : kk, A1);
        body(kk, A0);
        loadA(kk + 2 < k_hi ? kk + 2 : kk, A0);
        if (kk + 1 < k_hi) body(kk + 1, A1);
    }

    // Cross-wave K-reduction through LDS (aliases staging tile).
    __syncthreads();
    float4* scratch = (float4*)sh;
    #pragma unroll
    for (int mt = 0; mt < 4; ++mt)
        #pragma unroll
        for (int nf = 0; nf < 2; ++nf) {
            FragU u; u.f = acc[mt][nf];
            scratch[(q * 8 + mt * 2 + nf) * 64 + lane] = u.f4;
        }
    __syncthreads();

    // Wave q finalizes mtile q (rows mblk*64+q*16..+15, all 32 columns).
    #pragma unroll
    for (int nf = 0; nf < 2; ++nf) {
        float4 s = scratch[(q * 2 + nf) * 64 + lane];
        #pragma unroll
        for (int w = 1; w < 4; ++w) {
            float4 p = scratch[(w * 8 + q * 2 + nf) * 64 + lane];
            s.x += p.x; s.y += p.y; s.z += p.z; s.w += p.w;
        }
        const int rbase = mblk * 64 + q * 16 + 4 * oct;     // rows rbase..+3
        const float4 b4 = *(const float4*)(biasr + rbase);
        const int f = rbase >> 2;
        float gi = sigmoid_f(s.x + b4.x);
        float gf = sigmoid_f(s.y + b4.y);
        float go = sigmoid_f(s.z + b4.z);
        float gg = tanh_f(s.w + b4.w);
        const int l   = l0 + nf * 16 + l16;
        const int idx = (b * F_CH + f) * L_LEN + l;
        float cp = c_in[idx];
        float cn = gf * cp + gi * gg;
        float hn = go * tanh_f(cn);
        c_out[idx] = cn;
        if (h_out_f32) h_out_f32[idx] = hn;
        hp_out[idx] = pack_f32(hn);
    }
}

extern "C" void kernel_launch(void* const* d_in, const int* in_sizes, int n_in,
                              void* d_out, int out_size, void* d_ws, size_t ws_size,
                              hipStream_t stream)
{
    const float* x  = (const float*)d_in[0];  // [B,T,Cin,L]
    const float* W0 = (const float*)d_in[1];  // [512,192,5]
    const float* b0 = (const float*)d_in[2];  // [512]
    const float* W1 = (const float*)d_in[3];  // [512,256,5]
    const float* b1 = (const float*)d_in[4];  // [512]
    const float* h0 = (const float*)d_in[5];  // [B,F,L]
    const float* c0 = (const float*)d_in[6];
    const float* h1 = (const float*)d_in[7];
    const float* c1 = (const float*)d_in[8];
    float* out = (float*)d_out;               // [T,B,F,L]

    const int S = S_BFL;
    float* ws  = (float*)d_ws;
    float* c0w = ws;                          // S floats
    float* c1w = ws + S;                      // S floats
    float* br0 = ws + 2 * S;                  // 512
    float* br1 = br0 + 512;
    uint_t* hp0a = (uint_t*)(ws + 2 * S + 1024);
    uint_t* hp0b = hp0a + S;
    uint_t* hp1a = hp0b + S;
    uint_t* hp1b = hp1a + S;
    ushort_t* Ahi0 = (ushort_t*)(hp1b + S);
    const int N0 = 512 * 192 * 5;             // 491520
    const int N1 = 512 * 256 * 5;             // 655360
    ushort_t* Alo0 = Ahi0 + N0;
    ushort_t* Ahi1 = Alo0 + N0;
    ushort_t* Alo1 = Ahi1 + N1;

    // Pre-pass (graph-safe, every call).
    convert_w<192><<<dim3(240), dim3(256), 0, stream>>>(W0, Ahi0, Alo0);
    convert_w<256><<<dim3(320), dim3(256), 0, stream>>>(W1, Ahi1, Alo1);
    remap_bias<<<dim3(4), dim3(256), 0, stream>>>(b0, b1, br0, br1);
    pack_init<<<dim3((S + 255) / 256), dim3(256), 0, stream>>>(h0, h1, hp0b, hp1b);

    dim3 grid(512), block(256);
    for (int t = 0; t < T_SZ; ++t) {
        uint_t* hp0r = (t & 1) ? hp0a : hp0b;
        uint_t* hp0w = (t & 1) ? hp0b : hp0a;
        uint_t* hp1r = (t & 1) ? hp1a : hp1b;
        uint_t* hp1w = (t & 1) ? hp1b : hp1a;

        step_mfma<CIN, 192, true><<<grid, block, 0, stream>>>(
            x + t * CIN * L_LEN, T_SZ * CIN * L_LEN, (const uint_t*)nullptr,
            hp0r, Ahi0, Alo0, br0,
            t ? (const float*)c0w : c0, c0w,
            (float*)nullptr, hp0w);

        step_mfma<F_CH, 256, false><<<grid, block, 0, stream>>>(
            (const float*)nullptr, 0, hp0w,
            hp1r, Ahi1, Alo1, br1,
            t ? (const float*)c1w : c1, c1w,
            out + (size_t)t * S, hp1w);
    }
}